// Round 19
// baseline (18.543 us; speedup 1.0000x reference)
//
#include <hip/hip_runtime.h>
#include <math.h>

#define NTOK 256
#define DD 16
#define BDIM 512

typedef short short8 __attribute__((ext_vector_type(8)));
typedef float f32x16 __attribute__((ext_vector_type(16)));
typedef float v2f __attribute__((ext_vector_type(2)));
typedef unsigned int u32;
typedef unsigned long long u64;
#define FMA2 __builtin_elementwise_fma

__device__ __forceinline__ u32 f2bf(float f) {
    u32 u = __float_as_uint(f);
    u += 0x7FFFu + ((u >> 16) & 1u);
    return u >> 16;
}
struct U128 { u64 a, b; };
__device__ __forceinline__ short8 ld8(const unsigned short* p) {
    U128 t;
    t.a = *(const u64*)(p);
    t.b = *(const u64*)(p + 4);
    return __builtin_bit_cast(short8, t);
}
__device__ __forceinline__ v2f ld2(const float* p) {   // 8B-aligned pair load
    return *(const v2f*)p;
}
// pack 16 f32 (reg t -> k-offset pat(t,hi)=(t&3)+8*(t>>2)+4*hi) into two
// fragment short8s with k = 8*hi+e (f0: k 0..15, f1: k 16..31). HW-validated R3/R4/R6.
__device__ __forceinline__ void pack_swap16(f32x16 p, short8& f0, short8& f1) {
    u32 W00, W01, W10, W11, W20, W21, W30, W31;
    asm("v_cvt_pk_bf16_f32 %0, %1, %2" : "=v"(W00) : "v"(p[0]),  "v"(p[1]));
    asm("v_cvt_pk_bf16_f32 %0, %1, %2" : "=v"(W01) : "v"(p[2]),  "v"(p[3]));
    asm("v_cvt_pk_bf16_f32 %0, %1, %2" : "=v"(W10) : "v"(p[4]),  "v"(p[5]));
    asm("v_cvt_pk_bf16_f32 %0, %1, %2" : "=v"(W11) : "v"(p[6]),  "v"(p[7]));
    asm("v_cvt_pk_bf16_f32 %0, %1, %2" : "=v"(W20) : "v"(p[8]),  "v"(p[9]));
    asm("v_cvt_pk_bf16_f32 %0, %1, %2" : "=v"(W21) : "v"(p[10]), "v"(p[11]));
    asm("v_cvt_pk_bf16_f32 %0, %1, %2" : "=v"(W30) : "v"(p[12]), "v"(p[13]));
    asm("v_cvt_pk_bf16_f32 %0, %1, %2" : "=v"(W31) : "v"(p[14]), "v"(p[15]));
    asm("v_permlane32_swap_b32 %0, %1" : "+v"(W00), "+v"(W10));
    asm("v_permlane32_swap_b32 %0, %1" : "+v"(W01), "+v"(W11));
    asm("v_permlane32_swap_b32 %0, %1" : "+v"(W20), "+v"(W30));
    asm("v_permlane32_swap_b32 %0, %1" : "+v"(W21), "+v"(W31));
    struct { u32 x, y, z, w; } i0{W00, W01, W10, W11}, i1{W20, W21, W30, W31};
    f0 = __builtin_bit_cast(short8, i0);
    f1 = __builtin_bit_cast(short8, i1);
}
// exact-GELU (A&S 7.1.26 erf, |err|<=1.5e-7), two elements at once.
__device__ __forceinline__ v2f gelu2(float va, float vb) {
    v2f v; v.x = va; v.y = vb;
    v2f xx = v * 0.70710678118654752f;
    float axa = fabsf(xx.x), axb = fabsf(xx.y);
    v2f t;
    t.x = __builtin_amdgcn_rcpf(__builtin_fmaf(0.3275911f, axa, 1.0f));
    t.y = __builtin_amdgcn_rcpf(__builtin_fmaf(0.3275911f, axb, 1.0f));
    v2f poly = FMA2(t, (v2f)(1.061405429f), (v2f)(-1.453152027f));
    poly = FMA2(t, poly, (v2f)(1.421413741f));
    poly = FMA2(t, poly, (v2f)(-0.284496736f));
    poly = FMA2(t, poly, (v2f)(0.254829592f));
    poly = poly * t;
    v2f E;
    E.x = __expf(-axa * axa);
    E.y = __expf(-axb * axb);
    v2f r = FMA2(-poly, E, (v2f)(1.0f));
    v2f e2;
    e2.x = copysignf(r.x, xx.x);
    e2.y = copysignf(r.y, xx.y);
    v2f hv = v * 0.5f;
    return FMA2(hv, e2, hv);
}

__global__ __launch_bounds__(BDIM, 4) void qab_kernel(
    const float* __restrict__ x,
    const float* __restrict__ ln1_g, const float* __restrict__ ln1_b,
    const float* __restrict__ angles,
    const float* __restrict__ ln2_g, const float* __restrict__ ln2_b,
    const float* __restrict__ w1, const float* __restrict__ b1,
    const float* __restrict__ w2, const float* __restrict__ b2,
    float* __restrict__ out)
{
    __shared__ alignas(16) unsigned short a_bf[NTOK][20];   // amplitudes bf16
    __shared__ alignas(16) unsigned short wa_bf[NTOK][20];  // log2e * Wa bf16
    __shared__ alignas(16) unsigned short vxT[17][268];     // |Wa|^T + ones row
    __shared__ alignas(16) unsigned short w1tb[64][20];     // w1^T bf16 [k][e]
    __shared__ alignas(16) unsigned short w2tb[16][68];     // w2^T bf16 [d][k]
    __shared__ alignas(16) float b1_lds[64];
    __shared__ alignas(16) float ln2g_lds[DD];
    __shared__ alignas(16) float ln2b_lds[DD];
    __shared__ alignas(16) float b2_lds[DD];

    const int b    = blockIdx.x;
    const int tid  = threadIdx.x;
    const int r    = tid & (NTOK - 1);
    const int q    = tid >> 8;
    const int w    = tid >> 6;
    const int l31  = tid & 31;
    const int hi   = (tid >> 5) & 1;
    const int lane = tid & 63;

    // issue residual-x loads early (row = my attention lane-row)
    const float* xres = x + ((size_t)b * NTOK + 32 * w + l31) * DD;
    const float4 xra = *(const float4*)(xres + 4 * hi);
    const float4 xrb = *(const float4*)(xres + 8 + 4 * hi);

    f32x16 zc;
    #pragma unroll
    for (int t = 0; t < 16; ++t) zc[t] = 0.0f;

    // ---------------- P0: LN1 + amp chain, packed math ------------------------
    float amp[DD];
    {
        const float* xrow = x + ((size_t)b * NTOK + r) * DD;
        v2f x2[8];
        #pragma unroll
        for (int qq = 0; qq < 4; ++qq) {
            float4 v = ((const float4*)xrow)[qq];
            x2[2*qq].x   = v.x; x2[2*qq].y   = v.y;
            x2[2*qq+1].x = v.z; x2[2*qq+1].y = v.w;
        }
        v2f s2 = (v2f)(0.0f);
        #pragma unroll
        for (int k = 0; k < 8; ++k) s2 += x2[k];
        float mu = (s2.x + s2.y) * (1.0f / DD);
        v2f muv = (v2f)(mu);
        v2f vs2 = (v2f)(0.0f);
        #pragma unroll
        for (int k = 0; k < 8; ++k) { v2f d = x2[k] - muv; vs2 = FMA2(d, d, vs2); }
        float var = (vs2.x + vs2.y) * (1.0f / DD);
        float rs = 1.0f / sqrtf(var + 1e-5f);
        v2f rsv = (v2f)(rs);
        float inp[DD];
        #pragma unroll
        for (int k = 0; k < 8; ++k) {
            v2f g2 = ld2(&ln1_g[2*k]);
            v2f b2v = ld2(&ln1_b[2*k]);
            v2f e = (x2[k] - muv) * rsv;
            v2f f = FMA2(e, g2, b2v) * 0.5f;
            inp[2*k] = f.x; inp[2*k+1] = f.y;
        }

        // Spherical decomposition reconstructs its input; track prefix^2 only.
        float P = 1.0f;
        #pragma unroll
        for (int i = 0; i < DD - 1; ++i) {
            float v = inp[i];
            float v2 = v * v;
            bool ok = v2 <= P;
            amp[i] = ok ? v : __builtin_amdgcn_sqrtf(P);
            P = ok ? __builtin_fmaf(-v, v, P) : 0.0f;
        }
        amp[DD - 1] = __builtin_amdgcn_sqrtf(P);
    }

    if (q == 0) {
        // ---- write a_bf + stage weights/consts ----
        u32 aw[8];
        #pragma unroll
        for (int k = 0; k < 8; ++k)
            asm("v_cvt_pk_bf16_f32 %0, %1, %2" : "=v"(aw[k]) : "v"(amp[2*k]), "v"(amp[2*k+1]));
        *(u64*)&a_bf[r][0]  = (u64)aw[0] | ((u64)aw[1] << 32);
        *(u64*)&a_bf[r][4]  = (u64)aw[2] | ((u64)aw[3] << 32);
        *(u64*)&a_bf[r][8]  = (u64)aw[4] | ((u64)aw[5] << 32);
        *(u64*)&a_bf[r][12] = (u64)aw[6] | ((u64)aw[7] << 32);
        for (int i = r; i < 64 * DD; i += NTOK) {
            w1tb[i & 63][i >> 6] = (unsigned short)f2bf(w1[i]);   // w1^T
            w2tb[i & 15][i >> 4] = (unsigned short)f2bf(w2[i]);   // w2^T
        }
        if (r >= 128 && r < 192) b1_lds[r - 128] = b1[r - 128];
        if (r >= 192 && r < 208) ln2g_lds[r - 192] = ln2_g[r - 192];
        if (r >= 208 && r < 224) ln2b_lds[r - 208] = ln2_b[r - 208];
        if (r >= 224 && r < 240) b2_lds[r - 224] = b2[r - 224];
        vxT[16][r] = 0x3F80;   // ones row -> softmax denominator
    } else {
        // ---- Wa = butterfly rotations, packed: {i',j'} = {cs,-sn}vi + {sn,cs}vj
        float sn_l = 0.0f, cs_l = 0.0f;
        if (lane < 32) __sincosf(angles[lane], &sn_l, &cs_l);
        #pragma unroll
        for (int s = 0; s < 4; ++s) {
            const int step = 1 << s;
            #pragma unroll
            for (int p = 0; p < 8; ++p) {
                const int i = ((p >> s) << (s + 1)) | (p & (step - 1));
                const int j = i + step;
                float sn = __shfl(sn_l, s * 8 + p, 64);   // v_readlane broadcast
                float cs = __shfl(cs_l, s * 8 + p, 64);
                v2f cv; cv.x = cs; cv.y = -sn;
                v2f sv; sv.x = sn; sv.y = cs;
                v2f res = FMA2(sv, (v2f)(amp[j]), cv * amp[i]);
                amp[i] = res.x; amp[j] = res.y;
            }
        }
        // wa_bf pre-scaled by log2(e): P2's exp(|S|) = single native v_exp_f32
        const float L2E = 1.4426950408889634f;
        u32 ww[8];
        #pragma unroll
        for (int k = 0; k < 8; ++k)
            asm("v_cvt_pk_bf16_f32 %0, %1, %2" : "=v"(ww[k])
                : "v"(amp[2*k] * L2E), "v"(amp[2*k+1] * L2E));
        *(u64*)&wa_bf[r][0]  = (u64)ww[0] | ((u64)ww[1] << 32);
        *(u64*)&wa_bf[r][4]  = (u64)ww[2] | ((u64)ww[3] << 32);
        *(u64*)&wa_bf[r][8]  = (u64)ww[4] | ((u64)ww[5] << 32);
        *(u64*)&wa_bf[r][12] = (u64)ww[6] | ((u64)ww[7] << 32);
        #pragma unroll
        for (int d = 0; d < DD; ++d)
            vxT[d][r] = (unsigned short)f2bf(fabsf(amp[d]));
    }
    __syncthreads();
    // ======== everything below is barrier-free and per-wave independent ========

    // ---------------- P2: attention, 2-deep software pipeline -----------------
    const int ncl = (l31 < 16) ? l31 : 16;   // vx A-frag row clamp (row16 = ones)
    f32x16 Oacc = zc;
    {
        short8 waf = ld8(&wa_bf[w * 32 + l31][8 * hi]);   // B-frag: col i, k = d
        short8 af[8];
        #pragma unroll
        for (int jt = 0; jt < 8; ++jt)
            af[jt] = ld8(&a_bf[jt * 32 + l31][8 * hi]);
        short8 va0 = ld8(&vxT[ncl][8 * hi]);
        short8 va1 = ld8(&vxT[ncl][16 + 8 * hi]);
        f32x16 S0 = __builtin_amdgcn_mfma_f32_32x32x16_bf16(af[0], waf, zc, 0, 0, 0);
        #pragma unroll
        for (int jt = 0; jt < 8; ++jt) {
            f32x16 Sn;
            if (jt < 7)
                Sn = __builtin_amdgcn_mfma_f32_32x32x16_bf16(af[jt + 1], waf, zc, 0, 0, 0);
            short8 nva0, nva1;
            if (jt < 7) {
                nva0 = ld8(&vxT[ncl][(jt + 1) * 32 + 8 * hi]);
                nva1 = ld8(&vxT[ncl][(jt + 1) * 32 + 16 + 8 * hi]);
            }
            f32x16 pv;
            #pragma unroll
            for (int t = 0; t < 16; ++t)
                pv[t] = __builtin_amdgcn_exp2f(fabsf(S0[t]));  // exp(|S|), native
            short8 pb0, pb1;
            pack_swap16(pv, pb0, pb1);                     // B-frags: col i, k = j
            Oacc = __builtin_amdgcn_mfma_f32_32x32x16_bf16(va0, pb0, Oacc, 0, 0, 0);
            Oacc = __builtin_amdgcn_mfma_f32_32x32x16_bf16(va1, pb1, Oacc, 0, 0, 0);
            S0 = Sn; va0 = nva0; va1 = nva1;
        }
    }

    // ---------------- P3: residual + LN2, packed (lane pairs) -----------------
    // Oacc[8] = row 16 (hi=0) / 20 (hi=1); rows 16..31 all = l (clamped ones-row)
    const float rl = 1.0f / Oacc[8];
    v2f rlv = (v2f)(rl);
    v2f xa0, xa1, xb0, xb1;
    xa0.x = xra.x; xa0.y = xra.y;  xa1.x = xra.z; xa1.y = xra.w;
    xb0.x = xrb.x; xb0.y = xrb.y;  xb1.x = xrb.z; xb1.y = xrb.w;
    v2f Oa0, Oa1, Ob0, Ob1;
    Oa0.x = Oacc[0]; Oa0.y = Oacc[1];  Oa1.x = Oacc[2]; Oa1.y = Oacc[3];
    Ob0.x = Oacc[4]; Ob0.y = Oacc[5];  Ob1.x = Oacc[6]; Ob1.y = Oacc[7];
    v2f o0 = FMA2(Oa0, rlv, xa0);
    v2f o1v = FMA2(Oa1, rlv, xa1);
    v2f o2v = FMA2(Ob0, rlv, xb0);
    v2f o3v = FMA2(Ob1, rlv, xb1);

    v2f ss = o0 + o1v + o2v + o3v;
    float s8 = ss.x + ss.y;
    float mu2 = (s8 + __shfl_xor(s8, 32, 64)) * (1.0f / DD);
    v2f muv2 = (v2f)(mu2);
    v2f d0 = o0 - muv2, d1 = o1v - muv2, d2 = o2v - muv2, d3 = o3v - muv2;
    v2f vv = FMA2(d0, d0, FMA2(d1, d1, FMA2(d2, d2, d3 * d3)));
    float v8 = vv.x + vv.y;
    float var2 = (v8 + __shfl_xor(v8, 32, 64)) * (1.0f / DD);
    v2f rs2v = (v2f)(1.0f / sqrtf(var2 + 1e-5f));

    v2f g0 = ld2(&ln2g_lds[4 * hi]);
    v2f g1 = ld2(&ln2g_lds[4 * hi + 2]);
    v2f g2 = ld2(&ln2g_lds[8 + 4 * hi]);
    v2f g3 = ld2(&ln2g_lds[8 + 4 * hi + 2]);
    v2f bb0 = ld2(&ln2b_lds[4 * hi]);
    v2f bb1 = ld2(&ln2b_lds[4 * hi + 2]);
    v2f bb2 = ld2(&ln2b_lds[8 + 4 * hi]);
    v2f bb3 = ld2(&ln2b_lds[8 + 4 * hi + 2]);
    v2f h0 = FMA2(d0 * rs2v, g0, bb0);
    v2f h1 = FMA2(d1 * rs2v, g1, bb1);
    v2f h2 = FMA2(d2 * rs2v, g2, bb2);
    v2f h3 = FMA2(d3 * rs2v, g3, bb3);

    short8 hB;   // B-frag (col = token, k = d)
    {
        u32 w0, w1u, w2u, w3;
        asm("v_cvt_pk_bf16_f32 %0, %1, %2" : "=v"(w0)  : "v"(h0.x), "v"(h0.y));
        asm("v_cvt_pk_bf16_f32 %0, %1, %2" : "=v"(w1u) : "v"(h1.x), "v"(h1.y));
        asm("v_cvt_pk_bf16_f32 %0, %1, %2" : "=v"(w2u) : "v"(h2.x), "v"(h2.y));
        asm("v_cvt_pk_bf16_f32 %0, %1, %2" : "=v"(w3)  : "v"(h3.x), "v"(h3.y));
        asm("s_nop 1\n\tv_permlane32_swap_b32 %0, %1" : "+v"(w0),  "+v"(w2u));
        asm("s_nop 1\n\tv_permlane32_swap_b32 %0, %1" : "+v"(w1u), "+v"(w3));
        struct { u32 x, y, z, w; } hw{w0, w1u, w2u, w3};
        hB = __builtin_bit_cast(short8, hw);
    }

    // ---------------- P4: MLP via MFMA, both H tiles in flight ----------------
    const int dcl = (l31 < 15) ? l31 : 15;   // w2 A-frag row clamp
    f32x16 O2 = zc;
    {
        const float4 c0 = *(const float4*)&b2_lds[4 * hi];
        const float4 c1 = *(const float4*)&b2_lds[8 + 4 * hi];
        O2[0] = c0.x; O2[1] = c0.y; O2[2] = c0.z; O2[3] = c0.w;
        O2[4] = c1.x; O2[5] = c1.y; O2[6] = c1.z; O2[7] = c1.w;
    }
    {
        f32x16 Hc0, Hc1;
        #pragma unroll
        for (int kblk = 0; kblk < 2; ++kblk) {
            const float* bp = &b1_lds[32 * kblk];
            const float4 c0 = *(const float4*)(bp + 4 * hi);
            const float4 c1 = *(const float4*)(bp + 8 + 4 * hi);
            const float4 c2 = *(const float4*)(bp + 16 + 4 * hi);
            const float4 c3 = *(const float4*)(bp + 24 + 4 * hi);
            f32x16& Hc = kblk ? Hc1 : Hc0;
            Hc[0]=c0.x; Hc[1]=c0.y; Hc[2]=c0.z; Hc[3]=c0.w;
            Hc[4]=c1.x; Hc[5]=c1.y; Hc[6]=c1.z; Hc[7]=c1.w;
            Hc[8]=c2.x; Hc[9]=c2.y; Hc[10]=c2.z; Hc[11]=c2.w;
            Hc[12]=c3.x; Hc[13]=c3.y; Hc[14]=c3.z; Hc[15]=c3.w;
        }
        short8 w1f0 = ld8(&w1tb[l31][8 * hi]);
        short8 w1f1 = ld8(&w1tb[32 + l31][8 * hi]);
        short8 w2a0 = ld8(&w2tb[dcl][8 * hi]);
        short8 w2a1 = ld8(&w2tb[dcl][16 + 8 * hi]);
        short8 w2b0 = ld8(&w2tb[dcl][32 + 8 * hi]);
        short8 w2b1 = ld8(&w2tb[dcl][48 + 8 * hi]);
        f32x16 H0 = __builtin_amdgcn_mfma_f32_32x32x16_bf16(w1f0, hB, Hc0, 0, 0, 0);
        f32x16 H1 = __builtin_amdgcn_mfma_f32_32x32x16_bf16(w1f1, hB, Hc1, 0, 0, 0);
        f32x16 gv0, gv1;
        #pragma unroll
        for (int t = 0; t < 16; t += 2) {
            v2f g = gelu2(H0[t], H0[t+1]);
            gv0[t] = g.x; gv0[t+1] = g.y;
        }
        short8 ga0, ga1;
        pack_swap16(gv0, ga0, ga1);
        #pragma unroll
        for (int t = 0; t < 16; t += 2) {
            v2f g = gelu2(H1[t], H1[t+1]);
            gv1[t] = g.x; gv1[t+1] = g.y;
        }
        short8 gb0, gb1;
        pack_swap16(gv1, gb0, gb1);
        O2 = __builtin_amdgcn_mfma_f32_32x32x16_bf16(w2a0, ga0, O2, 0, 0, 0);
        O2 = __builtin_amdgcn_mfma_f32_32x32x16_bf16(w2a1, ga1, O2, 0, 0, 0);
        O2 = __builtin_amdgcn_mfma_f32_32x32x16_bf16(w2b0, gb0, O2, 0, 0, 0);
        O2 = __builtin_amdgcn_mfma_f32_32x32x16_bf16(w2b1, gb1, O2, 0, 0, 0);
    }

    // ---------------- P5: out = o1 + O2 (+b2 already in O2), packed add -------
    {
        v2f O20, O21, O22, O23;
        O20.x = O2[0]; O20.y = O2[1];  O21.x = O2[2]; O21.y = O2[3];
        O22.x = O2[4]; O22.y = O2[5];  O23.x = O2[6]; O23.y = O2[7];
        v2f r0 = o0 + O20, r1 = o1v + O21, r2 = o2v + O22, r3 = o3v + O23;
        float* orow = out + ((size_t)b * NTOK + 32 * w + l31) * DD;
        float4 oa, ob;
        oa.x = r0.x; oa.y = r0.y; oa.z = r1.x; oa.w = r1.y;
        ob.x = r2.x; ob.y = r2.y; ob.z = r3.x; ob.w = r3.y;
        *(float4*)(orow + 4 * hi) = oa;
        *(float4*)(orow + 8 + 4 * hi) = ob;
    }
}

extern "C" void kernel_launch(void* const* d_in, const int* in_sizes, int n_in,
                              void* d_out, int out_size, void* d_ws, size_t ws_size,
                              hipStream_t stream) {
    const float* x     = (const float*)d_in[0];
    const float* ln1_g = (const float*)d_in[1];
    const float* ln1_b = (const float*)d_in[2];
    const float* ang   = (const float*)d_in[3];
    const float* ln2_g = (const float*)d_in[4];
    const float* ln2_b = (const float*)d_in[5];
    const float* w1    = (const float*)d_in[6];
    const float* b1    = (const float*)d_in[7];
    const float* w2    = (const float*)d_in[8];
    const float* b2    = (const float*)d_in[9];
    float* out = (float*)d_out;

    const int B = in_sizes[0] / (NTOK * DD);
    hipLaunchKernelGGL(qab_kernel, dim3(B), dim3(BDIM), 0, stream,
                       x, ln1_g, ln1_b, ang, ln2_g, ln2_b, w1, b1, w2, b2, out);
}

// Round 20
// 18.340 us; speedup vs baseline: 1.0111x; 1.0111x over previous
//
#include <hip/hip_runtime.h>
#include <math.h>

#define NTOK 256
#define DD 16
#define BDIM 512

typedef short short8 __attribute__((ext_vector_type(8)));
typedef float f32x16 __attribute__((ext_vector_type(16)));
typedef float v2f __attribute__((ext_vector_type(2)));
typedef unsigned int u32;
typedef unsigned long long u64;
#define FMA2 __builtin_elementwise_fma

__device__ __forceinline__ u32 f2bf(float f) {
    u32 u = __float_as_uint(f);
    u += 0x7FFFu + ((u >> 16) & 1u);
    return u >> 16;
}
struct U128 { u64 a, b; };
__device__ __forceinline__ short8 ld8(const unsigned short* p) {
    U128 t;
    t.a = *(const u64*)(p);
    t.b = *(const u64*)(p + 4);
    return __builtin_bit_cast(short8, t);
}
// pack 16 f32 (reg t -> k-offset pat(t,hi)=(t&3)+8*(t>>2)+4*hi) into two
// fragment short8s with k = 8*hi+e (f0: k 0..15, f1: k 16..31). HW-validated R3/R4/R6.
__device__ __forceinline__ void pack_swap16(f32x16 p, short8& f0, short8& f1) {
    u32 W00, W01, W10, W11, W20, W21, W30, W31;
    asm("v_cvt_pk_bf16_f32 %0, %1, %2" : "=v"(W00) : "v"(p[0]),  "v"(p[1]));
    asm("v_cvt_pk_bf16_f32 %0, %1, %2" : "=v"(W01) : "v"(p[2]),  "v"(p[3]));
    asm("v_cvt_pk_bf16_f32 %0, %1, %2" : "=v"(W10) : "v"(p[4]),  "v"(p[5]));
    asm("v_cvt_pk_bf16_f32 %0, %1, %2" : "=v"(W11) : "v"(p[6]),  "v"(p[7]));
    asm("v_cvt_pk_bf16_f32 %0, %1, %2" : "=v"(W20) : "v"(p[8]),  "v"(p[9]));
    asm("v_cvt_pk_bf16_f32 %0, %1, %2" : "=v"(W21) : "v"(p[10]), "v"(p[11]));
    asm("v_cvt_pk_bf16_f32 %0, %1, %2" : "=v"(W30) : "v"(p[12]), "v"(p[13]));
    asm("v_cvt_pk_bf16_f32 %0, %1, %2" : "=v"(W31) : "v"(p[14]), "v"(p[15]));
    asm("v_permlane32_swap_b32 %0, %1" : "+v"(W00), "+v"(W10));
    asm("v_permlane32_swap_b32 %0, %1" : "+v"(W01), "+v"(W11));
    asm("v_permlane32_swap_b32 %0, %1" : "+v"(W20), "+v"(W30));
    asm("v_permlane32_swap_b32 %0, %1" : "+v"(W21), "+v"(W31));
    struct { u32 x, y, z, w; } i0{W00, W01, W10, W11}, i1{W20, W21, W30, W31};
    f0 = __builtin_bit_cast(short8, i0);
    f1 = __builtin_bit_cast(short8, i1);
}
// exact-GELU (A&S 7.1.26 erf, |err|<=1.5e-7), two elements at once:
// polynomial + blend in packed f32 (v_pk_*), rcp/exp/copysign scalar.
__device__ __forceinline__ v2f gelu2(float va, float vb) {
    v2f v; v.x = va; v.y = vb;
    v2f xx = v * 0.70710678118654752f;
    float axa = fabsf(xx.x), axb = fabsf(xx.y);
    v2f t;
    t.x = __builtin_amdgcn_rcpf(__builtin_fmaf(0.3275911f, axa, 1.0f));
    t.y = __builtin_amdgcn_rcpf(__builtin_fmaf(0.3275911f, axb, 1.0f));
    v2f poly = FMA2(t, (v2f)(1.061405429f), (v2f)(-1.453152027f));
    poly = FMA2(t, poly, (v2f)(1.421413741f));
    poly = FMA2(t, poly, (v2f)(-0.284496736f));
    poly = FMA2(t, poly, (v2f)(0.254829592f));
    poly = poly * t;
    v2f E;
    E.x = __expf(-axa * axa);
    E.y = __expf(-axb * axb);
    v2f r = FMA2(-poly, E, (v2f)(1.0f));
    v2f e2;
    e2.x = copysignf(r.x, xx.x);
    e2.y = copysignf(r.y, xx.y);
    v2f hv = v * 0.5f;
    return FMA2(hv, e2, hv);
}

__global__ __launch_bounds__(BDIM, 4) void qab_kernel(
    const float* __restrict__ x,
    const float* __restrict__ ln1_g, const float* __restrict__ ln1_b,
    const float* __restrict__ angles,
    const float* __restrict__ ln2_g, const float* __restrict__ ln2_b,
    const float* __restrict__ w1, const float* __restrict__ b1,
    const float* __restrict__ w2, const float* __restrict__ b2,
    float* __restrict__ out)
{
    __shared__ alignas(16) unsigned short a_bf[NTOK][20];   // amplitudes bf16
    __shared__ alignas(16) unsigned short wa_bf[NTOK][20];  // log2e * Wa bf16
    __shared__ alignas(16) unsigned short vxT[17][268];     // |Wa|^T + ones row
    __shared__ alignas(16) unsigned short w1tb[64][20];     // w1^T bf16 [k][e]
    __shared__ alignas(16) unsigned short w2tb[16][68];     // w2^T bf16 [d][k]
    __shared__ alignas(16) float b1_lds[64];
    __shared__ alignas(16) float ln2g_lds[DD];
    __shared__ alignas(16) float ln2b_lds[DD];
    __shared__ alignas(16) float b2_lds[DD];

    const int b    = blockIdx.x;
    const int tid  = threadIdx.x;
    const int r    = tid & (NTOK - 1);
    const int q    = tid >> 8;
    const int w    = tid >> 6;
    const int l31  = tid & 31;
    const int hi   = (tid >> 5) & 1;
    const int lane = tid & 63;

    // issue residual-x loads early (row = my attention lane-row)
    const float* xres = x + ((size_t)b * NTOK + 32 * w + l31) * DD;
    const float4 xra = *(const float4*)(xres + 4 * hi);
    const float4 xrb = *(const float4*)(xres + 8 + 4 * hi);

    f32x16 zc;
    #pragma unroll
    for (int t = 0; t < 16; ++t) zc[t] = 0.0f;

    // ---------------- P0: LN1 + amp chain (ALL threads; row r redundant x2) ---
    float amp[DD];
    {
        const float* xrow = x + ((size_t)b * NTOK + r) * DD;
        float xr[DD];
        #pragma unroll
        for (int qq = 0; qq < 4; ++qq) {
            float4 v = ((const float4*)xrow)[qq];
            xr[4*qq+0] = v.x; xr[4*qq+1] = v.y; xr[4*qq+2] = v.z; xr[4*qq+3] = v.w;
        }
        float mu = 0.0f;
        #pragma unroll
        for (int d = 0; d < DD; ++d) mu += xr[d];
        mu *= (1.0f / DD);
        float var = 0.0f;
        #pragma unroll
        for (int d = 0; d < DD; ++d) { float dv = xr[d] - mu; var += dv * dv; }
        var *= (1.0f / DD);
        float rs = 1.0f / sqrtf(var + 1e-5f);
        float inp[DD];
        #pragma unroll
        for (int d = 0; d < DD; ++d)
            inp[d] = ((xr[d] - mu) * rs * ln1_g[d] + ln1_b[d]) * 0.5f;

        // Spherical decomposition reconstructs its input; track prefix^2 only.
        float P = 1.0f;
        #pragma unroll
        for (int i = 0; i < DD - 1; ++i) {
            float v = inp[i];
            float v2 = v * v;
            bool ok = v2 <= P;
            amp[i] = ok ? v : __builtin_amdgcn_sqrtf(P);
            P = ok ? __builtin_fmaf(-v, v, P) : 0.0f;
        }
        amp[DD - 1] = __builtin_amdgcn_sqrtf(P);
    }

    if (q == 0) {
        // ---- write a_bf + stage weights/consts ----
        u32 aw[8];
        #pragma unroll
        for (int k = 0; k < 8; ++k)
            asm("v_cvt_pk_bf16_f32 %0, %1, %2" : "=v"(aw[k]) : "v"(amp[2*k]), "v"(amp[2*k+1]));
        *(u64*)&a_bf[r][0]  = (u64)aw[0] | ((u64)aw[1] << 32);
        *(u64*)&a_bf[r][4]  = (u64)aw[2] | ((u64)aw[3] << 32);
        *(u64*)&a_bf[r][8]  = (u64)aw[4] | ((u64)aw[5] << 32);
        *(u64*)&a_bf[r][12] = (u64)aw[6] | ((u64)aw[7] << 32);
        for (int i = r; i < 64 * DD; i += NTOK) {
            w1tb[i & 63][i >> 6] = (unsigned short)f2bf(w1[i]);   // w1^T
            w2tb[i & 15][i >> 4] = (unsigned short)f2bf(w2[i]);   // w2^T
        }
        if (r >= 128 && r < 192) b1_lds[r - 128] = b1[r - 128];
        if (r >= 192 && r < 208) ln2g_lds[r - 192] = ln2_g[r - 192];
        if (r >= 208 && r < 224) ln2b_lds[r - 208] = ln2_b[r - 208];
        if (r >= 224 && r < 240) b2_lds[r - 224] = b2[r - 224];
        vxT[16][r] = 0x3F80;   // ones row -> softmax denominator
    } else {
        // ---- Wa = butterfly rotations applied directly to amp (in place) ----
        float sn_l = 0.0f, cs_l = 0.0f;
        if (lane < 32) __sincosf(angles[lane], &sn_l, &cs_l);
        #pragma unroll
        for (int s = 0; s < 4; ++s) {
            const int step = 1 << s;
            #pragma unroll
            for (int p = 0; p < 8; ++p) {
                const int i = ((p >> s) << (s + 1)) | (p & (step - 1));
                const int j = i + step;
                float sn = __shfl(sn_l, s * 8 + p, 64);   // v_readlane broadcast
                float cs = __shfl(cs_l, s * 8 + p, 64);
                float vi = amp[i], vj = amp[j];
                amp[i] =  cs * vi + sn * vj;
                amp[j] = -sn * vi + cs * vj;
            }
        }
        // wa_bf pre-scaled by log2(e): P2's exp(|S|) = single native v_exp_f32
        const float L2E = 1.4426950408889634f;
        u32 ww[8];
        #pragma unroll
        for (int k = 0; k < 8; ++k)
            asm("v_cvt_pk_bf16_f32 %0, %1, %2" : "=v"(ww[k])
                : "v"(amp[2*k] * L2E), "v"(amp[2*k+1] * L2E));
        *(u64*)&wa_bf[r][0]  = (u64)ww[0] | ((u64)ww[1] << 32);
        *(u64*)&wa_bf[r][4]  = (u64)ww[2] | ((u64)ww[3] << 32);
        *(u64*)&wa_bf[r][8]  = (u64)ww[4] | ((u64)ww[5] << 32);
        *(u64*)&wa_bf[r][12] = (u64)ww[6] | ((u64)ww[7] << 32);
        #pragma unroll
        for (int d = 0; d < DD; ++d)
            vxT[d][r] = (unsigned short)f2bf(fabsf(amp[d]));
    }
    __syncthreads();
    // ======== everything below is barrier-free and per-wave independent ========

    // ---------------- P2: attention, 2-deep software pipeline -----------------
    const int ncl = (l31 < 16) ? l31 : 16;   // vx A-frag row clamp (row16 = ones)
    f32x16 Oacc = zc;
    {
        short8 waf = ld8(&wa_bf[w * 32 + l31][8 * hi]);   // B-frag: col i, k = d
        // preload ALL af A-frags (takes ds_read latency off the chain)
        short8 af[8];
        #pragma unroll
        for (int jt = 0; jt < 8; ++jt)
            af[jt] = ld8(&a_bf[jt * 32 + l31][8 * hi]);
        short8 va0 = ld8(&vxT[ncl][8 * hi]);
        short8 va1 = ld8(&vxT[ncl][16 + 8 * hi]);
        // S pipeline: S for jt+1 issues before pv-processing of jt
        f32x16 S0 = __builtin_amdgcn_mfma_f32_32x32x16_bf16(af[0], waf, zc, 0, 0, 0);
        #pragma unroll
        for (int jt = 0; jt < 8; ++jt) {
            f32x16 Sn;
            if (jt < 7)
                Sn = __builtin_amdgcn_mfma_f32_32x32x16_bf16(af[jt + 1], waf, zc, 0, 0, 0);
            short8 nva0, nva1;
            if (jt < 7) {
                nva0 = ld8(&vxT[ncl][(jt + 1) * 32 + 8 * hi]);
                nva1 = ld8(&vxT[ncl][(jt + 1) * 32 + 16 + 8 * hi]);
            }
            f32x16 pv;
            #pragma unroll
            for (int t = 0; t < 16; ++t)
                pv[t] = __builtin_amdgcn_exp2f(fabsf(S0[t]));  // exp(|S|), native
            short8 pb0, pb1;
            pack_swap16(pv, pb0, pb1);                     // B-frags: col i, k = j
            Oacc = __builtin_amdgcn_mfma_f32_32x32x16_bf16(va0, pb0, Oacc, 0, 0, 0);
            Oacc = __builtin_amdgcn_mfma_f32_32x32x16_bf16(va1, pb1, Oacc, 0, 0, 0);
            S0 = Sn; va0 = nva0; va1 = nva1;
        }
    }

    // ---------------- P3: residual + LN2, in-register (lane pairs) ------------
    // Oacc[8] = row 16 (hi=0) / 20 (hi=1); rows 16..31 all = l (clamped ones-row)
    const float rl = 1.0f / Oacc[8];
    float o1[8];
    o1[0] = xra.x + Oacc[0] * rl;  o1[1] = xra.y + Oacc[1] * rl;
    o1[2] = xra.z + Oacc[2] * rl;  o1[3] = xra.w + Oacc[3] * rl;
    o1[4] = xrb.x + Oacc[4] * rl;  o1[5] = xrb.y + Oacc[5] * rl;
    o1[6] = xrb.z + Oacc[6] * rl;  o1[7] = xrb.w + Oacc[7] * rl;

    float s8 = 0.0f;
    #pragma unroll
    for (int t = 0; t < 8; ++t) s8 += o1[t];
    float mu2 = (s8 + __shfl_xor(s8, 32, 64)) * (1.0f / DD);
    float v8 = 0.0f;
    #pragma unroll
    for (int t = 0; t < 8; ++t) { float dv = o1[t] - mu2; v8 += dv * dv; }
    float var2 = (v8 + __shfl_xor(v8, 32, 64)) * (1.0f / DD);
    float rs2 = 1.0f / sqrtf(var2 + 1e-5f);

    const float4 g0v = *(const float4*)&ln2g_lds[4 * hi];
    const float4 g1v = *(const float4*)&ln2g_lds[8 + 4 * hi];
    const float4 bb0 = *(const float4*)&ln2b_lds[4 * hi];
    const float4 bb1 = *(const float4*)&ln2b_lds[8 + 4 * hi];
    float h[8];
    h[0] = (o1[0]-mu2)*rs2*g0v.x + bb0.x;  h[1] = (o1[1]-mu2)*rs2*g0v.y + bb0.y;
    h[2] = (o1[2]-mu2)*rs2*g0v.z + bb0.z;  h[3] = (o1[3]-mu2)*rs2*g0v.w + bb0.w;
    h[4] = (o1[4]-mu2)*rs2*g1v.x + bb1.x;  h[5] = (o1[5]-mu2)*rs2*g1v.y + bb1.y;
    h[6] = (o1[6]-mu2)*rs2*g1v.z + bb1.z;  h[7] = (o1[7]-mu2)*rs2*g1v.w + bb1.w;

    short8 hB;   // B-frag (col = token, k = d)
    {
        u32 w0, w1u, w2u, w3;
        asm("v_cvt_pk_bf16_f32 %0, %1, %2" : "=v"(w0)  : "v"(h[0]), "v"(h[1]));
        asm("v_cvt_pk_bf16_f32 %0, %1, %2" : "=v"(w1u) : "v"(h[2]), "v"(h[3]));
        asm("v_cvt_pk_bf16_f32 %0, %1, %2" : "=v"(w2u) : "v"(h[4]), "v"(h[5]));
        asm("v_cvt_pk_bf16_f32 %0, %1, %2" : "=v"(w3)  : "v"(h[6]), "v"(h[7]));
        asm("s_nop 1\n\tv_permlane32_swap_b32 %0, %1" : "+v"(w0),  "+v"(w2u));
        asm("s_nop 1\n\tv_permlane32_swap_b32 %0, %1" : "+v"(w1u), "+v"(w3));
        struct { u32 x, y, z, w; } hw{w0, w1u, w2u, w3};
        hB = __builtin_bit_cast(short8, hw);
    }

    // ---------------- P4: MLP via MFMA, both H tiles in flight ----------------
    const int dcl = (l31 < 15) ? l31 : 15;   // w2 A-frag row clamp
    f32x16 O2 = zc;
    {
        const float4 c0 = *(const float4*)&b2_lds[4 * hi];
        const float4 c1 = *(const float4*)&b2_lds[8 + 4 * hi];
        O2[0] = c0.x; O2[1] = c0.y; O2[2] = c0.z; O2[3] = c0.w;
        O2[4] = c1.x; O2[5] = c1.y; O2[6] = c1.z; O2[7] = c1.w;
    }
    {
        f32x16 Hc0, Hc1;
        #pragma unroll
        for (int kblk = 0; kblk < 2; ++kblk) {
            const float* bp = &b1_lds[32 * kblk];
            const float4 c0 = *(const float4*)(bp + 4 * hi);
            const float4 c1 = *(const float4*)(bp + 8 + 4 * hi);
            const float4 c2 = *(const float4*)(bp + 16 + 4 * hi);
            const float4 c3 = *(const float4*)(bp + 24 + 4 * hi);
            f32x16& Hc = kblk ? Hc1 : Hc0;
            Hc[0]=c0.x; Hc[1]=c0.y; Hc[2]=c0.z; Hc[3]=c0.w;
            Hc[4]=c1.x; Hc[5]=c1.y; Hc[6]=c1.z; Hc[7]=c1.w;
            Hc[8]=c2.x; Hc[9]=c2.y; Hc[10]=c2.z; Hc[11]=c2.w;
            Hc[12]=c3.x; Hc[13]=c3.y; Hc[14]=c3.z; Hc[15]=c3.w;
        }
        short8 w1f0 = ld8(&w1tb[l31][8 * hi]);
        short8 w1f1 = ld8(&w1tb[32 + l31][8 * hi]);
        short8 w2a0 = ld8(&w2tb[dcl][8 * hi]);
        short8 w2a1 = ld8(&w2tb[dcl][16 + 8 * hi]);
        short8 w2b0 = ld8(&w2tb[dcl][32 + 8 * hi]);
        short8 w2b1 = ld8(&w2tb[dcl][48 + 8 * hi]);
        // both H tiles issue back-to-back; gelu/pack overlap their latency
        f32x16 H0 = __builtin_amdgcn_mfma_f32_32x32x16_bf16(w1f0, hB, Hc0, 0, 0, 0);
        f32x16 H1 = __builtin_amdgcn_mfma_f32_32x32x16_bf16(w1f1, hB, Hc1, 0, 0, 0);
        f32x16 gv0, gv1;
        #pragma unroll
        for (int t = 0; t < 16; t += 2) {
            v2f g = gelu2(H0[t], H0[t+1]);
            gv0[t] = g.x; gv0[t+1] = g.y;
        }
        short8 ga0, ga1;
        pack_swap16(gv0, ga0, ga1);
        #pragma unroll
        for (int t = 0; t < 16; t += 2) {
            v2f g = gelu2(H1[t], H1[t+1]);
            gv1[t] = g.x; gv1[t+1] = g.y;
        }
        short8 gb0, gb1;
        pack_swap16(gv1, gb0, gb1);
        O2 = __builtin_amdgcn_mfma_f32_32x32x16_bf16(w2a0, ga0, O2, 0, 0, 0);
        O2 = __builtin_amdgcn_mfma_f32_32x32x16_bf16(w2a1, ga1, O2, 0, 0, 0);
        O2 = __builtin_amdgcn_mfma_f32_32x32x16_bf16(w2b0, gb0, O2, 0, 0, 0);
        O2 = __builtin_amdgcn_mfma_f32_32x32x16_bf16(w2b1, gb1, O2, 0, 0, 0);
    }

    // ---------------- P5: out = o1 + O2 (+b2 already in O2), direct store -----
    {
        float* orow = out + ((size_t)b * NTOK + 32 * w + l31) * DD;
        float4 oa, ob;
        oa.x = o1[0] + O2[0]; oa.y = o1[1] + O2[1];
        oa.z = o1[2] + O2[2]; oa.w = o1[3] + O2[3];
        ob.x = o1[4] + O2[4]; ob.y = o1[5] + O2[5];
        ob.z = o1[6] + O2[6]; ob.w = o1[7] + O2[7];
        *(float4*)(orow + 4 * hi) = oa;
        *(float4*)(orow + 8 + 4 * hi) = ob;
    }
}

extern "C" void kernel_launch(void* const* d_in, const int* in_sizes, int n_in,
                              void* d_out, int out_size, void* d_ws, size_t ws_size,
                              hipStream_t stream) {
    const float* x     = (const float*)d_in[0];
    const float* ln1_g = (const float*)d_in[1];
    const float* ln1_b = (const float*)d_in[2];
    const float* ang   = (const float*)d_in[3];
    const float* ln2_g = (const float*)d_in[4];
    const float* ln2_b = (const float*)d_in[5];
    const float* w1    = (const float*)d_in[6];
    const float* b1    = (const float*)d_in[7];
    const float* w2    = (const float*)d_in[8];
    const float* b2    = (const float*)d_in[9];
    float* out = (float*)d_out;

    const int B = in_sizes[0] / (NTOK * DD);
    hipLaunchKernelGGL(qab_kernel, dim3(B), dim3(BDIM), 0, stream,
                       x, ln1_g, ln1_b, ang, ln2_g, ln2_b, w1, b1, w2, b2, out);
}